// Round 2
// baseline (469.469 us; speedup 1.0000x reference)
//
#include <hip/hip_runtime.h>
#include <math.h>

// Problem constants (B=8, H=8, S=16384, Dv=64, d_k=1)
#define S_LEN 16384
#define DV    64
#define NBH   64             // B*H
#define NBLK  16             // stage-1 blocks per (b,h)
#define CHUNK (S_LEN / NBLK) // 1024 rows per stage-1 block

// out[b,h,s,e] = Q[s] * (sum_s K[s]*V[s,e]) / (||Q|| * ||K||)   per (b,h)
//
// Workspace layout (floats):
//   pktv[NBH][NBLK][DV]  : partial K^T V        (64*16*64)
//   pq  [NBH][NBLK]      : partial sum Q^2
//   pk  [NBH][NBLK]      : partial sum K^2
//   fk  [NBH][DV]        : finalized ktv / (||Q||*||K||)

// ---------------- Stage 1: partial ktv + partial norms over a chunk ----------------
// grid = NBH*NBLK blocks, 256 threads.
__global__ __launch_bounds__(256) void stage1_partial(
    const float* __restrict__ Q, const float* __restrict__ K,
    const float* __restrict__ V,
    float* __restrict__ pktv, float* __restrict__ pq, float* __restrict__ pk) {
    const int bh  = blockIdx.x >> 4;
    const int blk = blockIdx.x & 15;
    const int tid = threadIdx.x;
    const int e4  = tid & 15;
    const int sg  = tid >> 4;

    const float*  Kb = K + (size_t)bh * S_LEN;
    const float4* Vb = (const float4*)(V + (size_t)bh * S_LEN * DV);

    const int s0 = blk * CHUNK;

    // --- norm partials: 1024 floats of Q and K for this chunk, 256 float4 each
    const float4* Qc4 = (const float4*)(Q + (size_t)bh * S_LEN + s0);
    const float4* Kc4 = (const float4*)(Kb + s0);
    const float4 qv = Qc4[tid];
    const float4 kv = Kc4[tid];
    float q2 = qv.x * qv.x + qv.y * qv.y + qv.z * qv.z + qv.w * qv.w;
    float k2 = kv.x * kv.x + kv.y * kv.y + kv.z * kv.z + kv.w * kv.w;

    // --- ktv partial over the chunk
    float4 acc = make_float4(0.f, 0.f, 0.f, 0.f);
    #pragma unroll 8
    for (int i = 0; i < CHUNK / 16; ++i) {
        const int s = s0 + i * 16 + sg;
        const float  k = Kb[s];                      // 4 distinct addrs/wave, broadcast
        const float4 v = Vb[(size_t)s * 16 + e4];    // wave reads 1KB contiguous
        acc.x += k * v.x; acc.y += k * v.y;
        acc.z += k * v.z; acc.w += k * v.w;
    }

    __shared__ float4 red[16][16];   // [sg][e4]
    __shared__ float rq[256], rk[256];
    red[sg][e4] = acc;
    rq[tid] = q2; rk[tid] = k2;
    __syncthreads();

    if (tid < DV) {                  // tid = e in [0,64)
        const float* base = (const float*)red;
        float s = 0.f;
        #pragma unroll
        for (int p = 0; p < 16; ++p) s += base[p * DV + tid];
        pktv[((size_t)bh * NBLK + blk) * DV + tid] = s;
    }
    // tree-reduce norms
    #pragma unroll
    for (int off = 128; off > 0; off >>= 1) {
        if (tid < off) { rq[tid] += rq[tid + off]; rk[tid] += rk[tid + off]; }
        __syncthreads();
    }
    if (tid == 0) {
        pq[bh * NBLK + blk] = rq[0];
        pk[bh * NBLK + blk] = rk[0];
    }
}

// ---------------- Stage 2: tiny partial reduce -> fk table ----------------
// grid = NBH blocks, 64 threads.
__global__ __launch_bounds__(64) void stage2_finalize(
    const float* __restrict__ pktv, const float* __restrict__ pq,
    const float* __restrict__ pk, float* __restrict__ fk) {
    const int bh  = blockIdx.x;
    const int tid = threadIdx.x;

    float s = 0.f;
    #pragma unroll
    for (int p = 0; p < NBLK; ++p)
        s += pktv[((size_t)bh * NBLK + p) * DV + tid];

    __shared__ float inv_norm;
    if (tid == 0) {
        float qss = 0.f, kss = 0.f;
        #pragma unroll
        for (int p = 0; p < NBLK; ++p) { qss += pq[bh * NBLK + p]; kss += pk[bh * NBLK + p]; }
        inv_norm = 1.0f / (sqrtf(qss) * sqrtf(kss));
    }
    __syncthreads();

    fk[(size_t)bh * DV + tid] = s * inv_norm;
}

// ---------------- Stage 3: rank-1 outer product write (grid-stride) ----------------
#define S3_BLOCKS 16384
__global__ __launch_bounds__(256) void stage3_outer(
    const float* __restrict__ Q, const float* __restrict__ fk,
    float4* __restrict__ out) {
    const size_t stride = (size_t)S3_BLOCKS * 256;
    size_t idx = (size_t)blockIdx.x * 256 + threadIdx.x;
    const size_t n4 = (size_t)NBH * S_LEN * (DV / 4);  // 16,777,216
    #pragma unroll
    for (int it = 0; it < 4; ++it, idx += stride) {
        const int e4 = (int)(idx & 15);
        const int s  = (int)((idx >> 4) & (S_LEN - 1));
        const int bh = (int)(idx >> 18);       // 16 * 16384 float4 per head
        const float  q = Q[(size_t)bh * S_LEN + s];
        const float4 f = ((const float4*)fk)[(size_t)bh * 16 + e4];
        out[idx] = make_float4(q * f.x, q * f.y, q * f.z, q * f.w);
    }
    (void)n4;
}

extern "C" void kernel_launch(void* const* d_in, const int* in_sizes, int n_in,
                              void* d_out, int out_size, void* d_ws, size_t ws_size,
                              hipStream_t stream) {
    const float* Q = (const float*)d_in[0];
    const float* K = (const float*)d_in[1];
    const float* V = (const float*)d_in[2];
    float* out = (float*)d_out;

    float* pktv = (float*)d_ws;                            // 64*16*64
    float* pq   = pktv + (size_t)NBH * NBLK * DV;          // 64*16
    float* pk   = pq + NBH * NBLK;                         // 64*16
    float* fk   = pk + NBH * NBLK;                         // 64*64

    stage1_partial<<<NBH * NBLK, 256, 0, stream>>>(Q, K, V, pktv, pq, pk);
    stage2_finalize<<<NBH, 64, 0, stream>>>(pktv, pq, pk, fk);
    stage3_outer<<<S3_BLOCKS, 256, 0, stream>>>(Q, fk, (float4*)out);
}